// Round 1
// 121.953 us; speedup vs baseline: 1.0047x; 1.0047x over previous
//
#include <hip/hip_runtime.h>

// PerturbedTopK: B=32, N=500, D=1024, K=16, sigma=0.05
// out[b, rank, idx] += 1/N for each sample's top-K (rank = ascending-index order).
//
// R3 algorithm (per sample = one wave, NO LDS, NO barriers, NO sort):
//   1. perturb: v = x + 0.05*noise (unfused, bit-matches numpy)
//   2. bisect threshold T until count(v > T) == 16 EXACTLY
//      (values are distinct fp32 w.p. ~1; seeded bracket [1.5, 2.8] covers the
//       16th order statistic of ~N(0,1) rows, probes are correct-always heuristics)
//   3. rank of each member = # members with smaller global index, computed via
//      ballot + mbcnt prefix counts in (chunk, lane, elem) = global-index order
//   4. one predicated atomicAdd per member
//   Tie fallback (interval collapses to 1 ulp without hitting 16): take all
//   strict members (v > hi) plus the lowest-index tie candidates (lo < v <= hi),
//   matching stable top_k semantics. Never taken on Gaussian data, kept for
//   correctness.

#define PTK_K     16
#define PTK_N     500
#define PTK_B     32
#define PTK_D     1024
#define PTK_SIGMA 0.05f

__device__ __forceinline__ int lanes_below(unsigned long long m) {
    // count of set bits in m at lane positions strictly below this lane
    return __builtin_amdgcn_mbcnt_hi((unsigned)(m >> 32),
           __builtin_amdgcn_mbcnt_lo((unsigned)m, 0u));
}

__global__ __launch_bounds__(256) void ptk_kernel(const float* __restrict__ x,
                                                  const float* __restrict__ noise,
                                                  float* __restrict__ out) {
    const int lane = threadIdx.x & 63;
    const int wv   = threadIdx.x >> 6;
    const int s    = blockIdx.x * 4 + wv;      // sample id (grid exact: 4000*4)
    const int b    = s / PTK_N;

    const float4* nz = (const float4*)(noise + (size_t)s * PTK_D);
    const float4* xr = (const float4*)(x + (size_t)b * PTK_D);

    // Each lane owns 16 elements: global index g = c*256 + lane*4 + r  (i = c*4+r)
    float v[16];
#pragma unroll
    for (int c = 0; c < 4; ++c) {
        float4 n4 = nz[c * 64 + lane];
        float4 x4 = xr[c * 64 + lane];
        // mul-then-add, unfused, to bit-match the numpy fp32 reference
        v[c * 4 + 0] = __fadd_rn(x4.x, __fmul_rn(n4.x, PTK_SIGMA));
        v[c * 4 + 1] = __fadd_rn(x4.y, __fmul_rn(n4.y, PTK_SIGMA));
        v[c * 4 + 2] = __fadd_rn(x4.z, __fmul_rn(n4.z, PTK_SIGMA));
        v[c * 4 + 3] = __fadd_rn(x4.w, __fmul_rn(n4.w, PTK_SIGMA));
    }

    auto countGT = [&](float T) {
        int cnt = 0;
#pragma unroll
        for (int i = 0; i < 16; ++i)
            cnt += __popcll(__ballot(v[i] > T));   // wave-uniform scalar count
        return cnt;
    };

    // ---- 2. bisect to count(v > T) == 16 exactly ----
    // |v| < 5 guaranteed for Gaussian data, so [-16,16] brackets everything.
    // Invariant: count(>lo) > 16 > count(>hi).
    float lo = -16.0f, hi = 16.0f;
    float Tsel = 0.0f;
    bool  exact = false;
    for (int it = 0; it < 200; ++it) {
        float T;
        if      (it == 0) T = 1.5f;             // seeded probes: typical 16th
        else if (it == 1) T = 2.8f;             // order stat of N(0,1) is ~2.16
        else              T = 0.5f * (lo + hi);
        if (T <= lo || T >= hi) {
            if (it < 2) continue;               // probe outside bracket: skip
            break;                              // interval collapsed -> ties
        }
        int cnt = countGT(T);
        if (cnt == PTK_K) { Tsel = T; exact = true; break; }
        if (cnt > PTK_K) lo = T; else hi = T;
    }

    // ---- membership flags (exactly 16 set across the wave) ----
    bool inf_[16];
    if (exact) {
#pragma unroll
        for (int i = 0; i < 16; ++i) inf_[i] = v[i] > Tsel;
    } else {
        // collapsed: all candidates in (lo, hi] share one value; fill the
        // remaining slots by lowest global index (stable top_k tie-break)
        bool strict_[16], tie_[16];
        int cs = 0;
#pragma unroll
        for (int i = 0; i < 16; ++i) {
            strict_[i] = v[i] > hi;
            cs += __popcll(__ballot(strict_[i]));
            tie_[i] = (v[i] > lo) && !strict_[i];
        }
        const int need = PTK_K - cs;
        int chunkpref = 0;
#pragma unroll
        for (int c = 0; c < 4; ++c) {
            unsigned long long tb[4];
#pragma unroll
            for (int r = 0; r < 4; ++r) tb[r] = __ballot(tie_[c * 4 + r]);
            int laneb = 0;
#pragma unroll
            for (int r = 0; r < 4; ++r) laneb += lanes_below(tb[r]);
            int local = 0;
#pragma unroll
            for (int r = 0; r < 4; ++r) {
                int before = chunkpref + laneb + local;
                inf_[c * 4 + r] = strict_[c * 4 + r] ||
                                  (tie_[c * 4 + r] && before < need);
                local += tie_[c * 4 + r] ? 1 : 0;
            }
#pragma unroll
            for (int r = 0; r < 4; ++r) chunkpref += __popcll(tb[r]);
        }
    }

    // ---- 3./4. rank by ascending global index via ballot-prefix; scatter ----
    float* outb = out + (size_t)b * PTK_K * PTK_D;
    int chunkpref = 0;
#pragma unroll
    for (int c = 0; c < 4; ++c) {
        unsigned long long ib[4];
#pragma unroll
        for (int r = 0; r < 4; ++r) ib[r] = __ballot(inf_[c * 4 + r]);
        int laneb = 0;
#pragma unroll
        for (int r = 0; r < 4; ++r) laneb += lanes_below(ib[r]);
        int local = 0;
#pragma unroll
        for (int r = 0; r < 4; ++r) {
            if (inf_[c * 4 + r]) {
                int rank = chunkpref + laneb + local;
                int g    = c * 256 + lane * 4 + r;
                atomicAdd(outb + (size_t)rank * PTK_D + g, 1.0f / (float)PTK_N);
            }
            local += inf_[c * 4 + r] ? 1 : 0;
        }
#pragma unroll
        for (int r = 0; r < 4; ++r) chunkpref += __popcll(ib[r]);
    }
}

extern "C" void kernel_launch(void* const* d_in, const int* in_sizes, int n_in,
                              void* d_out, int out_size, void* d_ws, size_t ws_size,
                              hipStream_t stream) {
    const float* x     = (const float*)d_in[0];
    const float* noise = (const float*)d_in[1];
    float*       out   = (float*)d_out;

    // harness poisons d_out with 0xAA before every timed launch
    hipMemsetAsync(out, 0, (size_t)out_size * sizeof(float), stream);

    const int samples = PTK_B * PTK_N;          // 16000
    const int blocks  = samples / 4;            // 4 waves (samples) per block
    ptk_kernel<<<blocks, 256, 0, stream>>>(x, noise, out);
}

// Round 2
// 108.573 us; speedup vs baseline: 1.1285x; 1.1232x over previous
//
#include <hip/hip_runtime.h>

// PerturbedTopK: B=32, N=500, D=1024, K=16, sigma=0.05
// out[b, rank, idx] += 1/N for each sample's top-K (rank = ascending-index order).
//
// R4 algorithm: two passes, ZERO global atomics on hot addresses.
//   Pass 1 (per sample = one wave, no LDS, no barriers, no sort):
//     1. perturb v = x + 0.05*noise (unfused, bit-matches numpy)
//     2. bisect threshold T until count(v > T) == 16 exactly (tie fallback kept)
//     3. rank via ballot+mbcnt prefix in global-index order
//     4. store the 16 sorted indices as u16 to workspace (sample-private, 32 B)
//   Pass 2 (one block per (b, rank), 512 blocks):
//     LDS u32 histogram of the 500 sample indices for this (b, rank);
//     out[d] = table[count], where table[k] = k-fold ITERATED fp32 sum of 1/N.
//     Iterated-add table reproduces the reference's repeated scatter-add
//     rounding bit-exactly (count * (1/N) would not). Integer aggregation is
//     order-independent, so bit-exactness survives the parallel histogram.
//   Pass 2 writes every output element -> no output memset needed.
//
// Why: R3 was atomic-bound. sigma=0.05 barely reorders x, so all 500 samples
// of a row hit the SAME ~16 output cells; 512 hot addresses x ~500-deep
// cross-XCD fp32 atomic chains ~= 40 us of line ping-pong (per-wave lifetime
// measured ~26k cycles vs ~3k of compute).

#define PTK_K     16
#define PTK_N     500
#define PTK_B     32
#define PTK_D     1024
#define PTK_SIGMA 0.05f

__device__ __forceinline__ int lanes_below(unsigned long long m) {
    return __builtin_amdgcn_mbcnt_hi((unsigned)(m >> 32),
           __builtin_amdgcn_mbcnt_lo((unsigned)m, 0u));
}

// ---------- shared per-wave top-16 selection (R3 logic) ----------
// Computes membership flags inf_[16] (exactly 16 set across the wave) for
// v[16] owned by this lane. Returns via inf_.
__device__ __forceinline__ void select_top16(const float v[16], bool inf_[16]) {
    auto countGT = [&](float T) {
        int cnt = 0;
#pragma unroll
        for (int i = 0; i < 16; ++i)
            cnt += __popcll(__ballot(v[i] > T));   // wave-uniform scalar count
        return cnt;
    };

    // bisect to count(v > T) == 16 exactly.
    // |v| < 5 for Gaussian data; [-16,16] brackets everything.
    // Invariant: count(>lo) > 16 > count(>hi).
    float lo = -16.0f, hi = 16.0f;
    float Tsel = 0.0f;
    bool  exact = false;
    for (int it = 0; it < 200; ++it) {
        float T;
        if      (it == 0) T = 1.5f;             // seeded probes: typical 16th
        else if (it == 1) T = 2.8f;             // order stat of N(0,1) ~2.16
        else              T = 0.5f * (lo + hi);
        if (T <= lo || T >= hi) {
            if (it < 2) continue;               // probe outside bracket: skip
            break;                              // interval collapsed -> ties
        }
        int cnt = countGT(T);
        if (cnt == PTK_K) { Tsel = T; exact = true; break; }
        if (cnt > PTK_K) lo = T; else hi = T;
    }

    if (exact) {
#pragma unroll
        for (int i = 0; i < 16; ++i) inf_[i] = v[i] > Tsel;
    } else {
        // collapsed: candidates in (lo, hi] share one value; fill remaining
        // slots by lowest global index (stable top_k tie-break)
        bool strict_[16], tie_[16];
        int cs = 0;
#pragma unroll
        for (int i = 0; i < 16; ++i) {
            strict_[i] = v[i] > hi;
            cs += __popcll(__ballot(strict_[i]));
            tie_[i] = (v[i] > lo) && !strict_[i];
        }
        const int need = PTK_K - cs;
        int chunkpref = 0;
#pragma unroll
        for (int c = 0; c < 4; ++c) {
            unsigned long long tb[4];
#pragma unroll
            for (int r = 0; r < 4; ++r) tb[r] = __ballot(tie_[c * 4 + r]);
            int laneb = 0;
#pragma unroll
            for (int r = 0; r < 4; ++r) laneb += lanes_below(tb[r]);
            int local = 0;
#pragma unroll
            for (int r = 0; r < 4; ++r) {
                int before = chunkpref + laneb + local;
                inf_[c * 4 + r] = strict_[c * 4 + r] ||
                                  (tie_[c * 4 + r] && before < need);
                local += tie_[c * 4 + r] ? 1 : 0;
            }
#pragma unroll
            for (int r = 0; r < 4; ++r) chunkpref += __popcll(tb[r]);
        }
    }
}

__device__ __forceinline__ void load_perturb(const float* __restrict__ x,
                                             const float* __restrict__ noise,
                                             int s, int b, int lane, float v[16]) {
    const float4* nz = (const float4*)(noise + (size_t)s * PTK_D);
    const float4* xr = (const float4*)(x + (size_t)b * PTK_D);
#pragma unroll
    for (int c = 0; c < 4; ++c) {
        float4 n4 = nz[c * 64 + lane];
        float4 x4 = xr[c * 64 + lane];
        // mul-then-add, unfused, to bit-match the numpy fp32 reference
        v[c * 4 + 0] = __fadd_rn(x4.x, __fmul_rn(n4.x, PTK_SIGMA));
        v[c * 4 + 1] = __fadd_rn(x4.y, __fmul_rn(n4.y, PTK_SIGMA));
        v[c * 4 + 2] = __fadd_rn(x4.z, __fmul_rn(n4.z, PTK_SIGMA));
        v[c * 4 + 3] = __fadd_rn(x4.w, __fmul_rn(n4.w, PTK_SIGMA));
    }
}

// ---------- Pass 1: per-sample top-16 -> u16 index list in workspace ----------
__global__ __launch_bounds__(256) void ptk_topk(const float* __restrict__ x,
                                                const float* __restrict__ noise,
                                                unsigned short* __restrict__ topk) {
    const int lane = threadIdx.x & 63;
    const int wv   = threadIdx.x >> 6;
    const int s    = blockIdx.x * 4 + wv;      // sample id (grid exact: 4000*4)
    const int b    = s / PTK_N;

    float v[16];
    load_perturb(x, noise, s, b, lane, v);

    bool inf_[16];
    select_top16(v, inf_);

    // rank by ascending global index via ballot-prefix; store u16 idx at rank
    unsigned short* dst = topk + (size_t)s * PTK_K;
    int chunkpref = 0;
#pragma unroll
    for (int c = 0; c < 4; ++c) {
        unsigned long long ib[4];
#pragma unroll
        for (int r = 0; r < 4; ++r) ib[r] = __ballot(inf_[c * 4 + r]);
        int laneb = 0;
#pragma unroll
        for (int r = 0; r < 4; ++r) laneb += lanes_below(ib[r]);
        int local = 0;
#pragma unroll
        for (int r = 0; r < 4; ++r) {
            if (inf_[c * 4 + r]) {
                int rank = chunkpref + laneb + local;
                int g    = c * 256 + lane * 4 + r;
                dst[rank] = (unsigned short)g;
            }
            local += inf_[c * 4 + r] ? 1 : 0;
        }
#pragma unroll
        for (int r = 0; r < 4; ++r) chunkpref += __popcll(ib[r]);
    }
}

// ---------- Pass 2: per-(b,rank) histogram -> out row ----------
__global__ __launch_bounds__(256) void ptk_hist(const unsigned short* __restrict__ topk,
                                                float* __restrict__ out) {
    const int br   = blockIdx.x;               // 0..511
    const int b    = br >> 4;
    const int rank = br & 15;
    const int t    = threadIdx.x;

    __shared__ unsigned int hist[PTK_D];
    __shared__ float        tbl[PTK_N + 1];

    for (int i = t; i < PTK_D; i += 256) hist[i] = 0u;
    __syncthreads();

    // thread 255 builds the iterated-add table (serial by construction) while
    // the other threads histogram; both chains ~2k cycles, they overlap.
    if (t == 255) {
        float sacc = 0.0f;
        tbl[0] = 0.0f;
        for (int k = 1; k <= PTK_N; ++k) {
            sacc = __fadd_rn(sacc, 1.0f / (float)PTK_N);
            tbl[k] = sacc;
        }
    }
    for (int n = t; n < PTK_N; n += 256) {
        unsigned short g = topk[((size_t)b * PTK_N + n) * PTK_K + rank];
        atomicAdd(&hist[g], 1u);
    }
    __syncthreads();

    float* orow = out + ((size_t)b * PTK_K + rank) * PTK_D;
    for (int i = t; i < PTK_D; i += 256) orow[i] = tbl[hist[i]];
}

// ---------- Fallback (R3): single kernel with global atomics ----------
__global__ __launch_bounds__(256) void ptk_fallback(const float* __restrict__ x,
                                                    const float* __restrict__ noise,
                                                    float* __restrict__ out) {
    const int lane = threadIdx.x & 63;
    const int wv   = threadIdx.x >> 6;
    const int s    = blockIdx.x * 4 + wv;
    const int b    = s / PTK_N;

    float v[16];
    load_perturb(x, noise, s, b, lane, v);

    bool inf_[16];
    select_top16(v, inf_);

    float* outb = out + (size_t)b * PTK_K * PTK_D;
    int chunkpref = 0;
#pragma unroll
    for (int c = 0; c < 4; ++c) {
        unsigned long long ib[4];
#pragma unroll
        for (int r = 0; r < 4; ++r) ib[r] = __ballot(inf_[c * 4 + r]);
        int laneb = 0;
#pragma unroll
        for (int r = 0; r < 4; ++r) laneb += lanes_below(ib[r]);
        int local = 0;
#pragma unroll
        for (int r = 0; r < 4; ++r) {
            if (inf_[c * 4 + r]) {
                int rank = chunkpref + laneb + local;
                int g    = c * 256 + lane * 4 + r;
                atomicAdd(outb + (size_t)rank * PTK_D + g, 1.0f / (float)PTK_N);
            }
            local += inf_[c * 4 + r] ? 1 : 0;
        }
#pragma unroll
        for (int r = 0; r < 4; ++r) chunkpref += __popcll(ib[r]);
    }
}

extern "C" void kernel_launch(void* const* d_in, const int* in_sizes, int n_in,
                              void* d_out, int out_size, void* d_ws, size_t ws_size,
                              hipStream_t stream) {
    const float* x     = (const float*)d_in[0];
    const float* noise = (const float*)d_in[1];
    float*       out   = (float*)d_out;

    const int samples = PTK_B * PTK_N;                       // 16000
    const size_t ws_needed = (size_t)samples * PTK_K * sizeof(unsigned short); // 512 KB

    if (d_ws != nullptr && ws_size >= ws_needed) {
        unsigned short* topk = (unsigned short*)d_ws;
        // pass 2 writes every out element -> no memset needed
        ptk_topk<<<samples / 4, 256, 0, stream>>>(x, noise, topk);
        ptk_hist<<<PTK_B * PTK_K, 256, 0, stream>>>(topk, out);
    } else {
        // harness poisons d_out with 0xAA before every timed launch
        hipMemsetAsync(out, 0, (size_t)out_size * sizeof(float), stream);
        ptk_fallback<<<samples / 4, 256, 0, stream>>>(x, noise, out);
    }
}

// Round 3
// 103.523 us; speedup vs baseline: 1.1836x; 1.0488x over previous
//
#include <hip/hip_runtime.h>

// PerturbedTopK: B=32, N=500, D=1024, K=16, sigma=0.05
// out[b, rank, idx] += 1/N for each sample's top-K (rank = ascending-index order).
//
// R5 = R4 (two-pass, zero hot global atomics) + pass-2 critical-path fixes:
//   - iterated-add table is now a COMPILE-TIME constexpr constant (clang
//     constexpr fp32 is exact IEEE-RN, bit-identical to the __fadd_rn chain
//     each block used to build serially: a 500-deep dependent-add chain on
//     every block's critical path, now deleted).
//   - workspace layout transposed to [b][rank][n] so pass-2's 500 index
//     reads are stride-1 coalesced u16 (pass-1's scattered stores are
//     fire-and-forget, never on its critical path).
//   - pass-2 vectorized: uint4 hist init/read, float4 output stores.
//   - bisect seeds tightened to [1.8, 2.55] (+-4sigma bracket of the 16th
//     order statistic of N(0,1) at D=1024); pure heuristic, fallback keeps
//     correctness for arbitrary data.
//
// History: R3 removed the bitonic sort (50->44 us); R4 removed the contended
// fp32 atomic scatter (sigma=0.05 makes all 500 samples of a row hit the same
// ~16 cells; ~500-deep cross-XCD RMW chains ~= 40 us). Kernels are now ~13 us
// combined; harness dur_us is dominated by its own 256 MB ws poison fill
// (41 us @ 82% HBM peak) + launch overhead.

#define PTK_K     16
#define PTK_N     500
#define PTK_B     32
#define PTK_D     1024
#define PTK_SIGMA 0.05f

// ---- compile-time iterated-add table: tbl.v[k] = k-fold fp32 sum of 1/N ----
// Reproduces the reference's repeated scatter-add rounding exactly; integer
// count aggregation is order-independent, so bit-exactness survives the
// parallel histogram.
struct PtkTbl { float v[PTK_N + 1]; };
static constexpr PtkTbl make_tbl() {
    PtkTbl t{};
    float s = 0.0f;
    t.v[0] = 0.0f;
    for (int k = 1; k <= PTK_N; ++k) {
        s = s + (1.0f / (float)PTK_N);   // constexpr fp32: exact IEEE RN
        t.v[k] = s;
    }
    return t;
}
__device__ __constant__ PtkTbl g_tbl = make_tbl();

__device__ __forceinline__ int lanes_below(unsigned long long m) {
    return __builtin_amdgcn_mbcnt_hi((unsigned)(m >> 32),
           __builtin_amdgcn_mbcnt_lo((unsigned)m, 0u));
}

// ---------- shared per-wave top-16 selection ----------
// Membership flags inf_[16] (exactly 16 set across the wave) for the 16
// elements v[] owned by this lane.
__device__ __forceinline__ void select_top16(const float v[16], bool inf_[16]) {
    auto countGT = [&](float T) {
        int cnt = 0;
#pragma unroll
        for (int i = 0; i < 16; ++i)
            cnt += __popcll(__ballot(v[i] > T));   // wave-uniform scalar count
        return cnt;
    };

    // bisect to count(v > T) == 16 exactly.
    // |v| < 5 for Gaussian data; [-16,16] brackets everything.
    // Invariant: count(>lo) > 16 > count(>hi).
    float lo = -16.0f, hi = 16.0f;
    float Tsel = 0.0f;
    bool  exact = false;
    for (int it = 0; it < 200; ++it) {
        float T;
        if      (it == 0) T = 1.80f;            // +-4sigma bracket of the 16th
        else if (it == 1) T = 2.55f;            // order stat of N(0,1), D=1024
        else              T = 0.5f * (lo + hi);
        if (T <= lo || T >= hi) {
            if (it < 2) continue;               // probe outside bracket: skip
            break;                              // interval collapsed -> ties
        }
        int cnt = countGT(T);
        if (cnt == PTK_K) { Tsel = T; exact = true; break; }
        if (cnt > PTK_K) lo = T; else hi = T;
    }

    if (exact) {
#pragma unroll
        for (int i = 0; i < 16; ++i) inf_[i] = v[i] > Tsel;
    } else {
        // collapsed: candidates in (lo, hi] share one value; fill remaining
        // slots by lowest global index (stable top_k tie-break)
        bool strict_[16], tie_[16];
        int cs = 0;
#pragma unroll
        for (int i = 0; i < 16; ++i) {
            strict_[i] = v[i] > hi;
            cs += __popcll(__ballot(strict_[i]));
            tie_[i] = (v[i] > lo) && !strict_[i];
        }
        const int need = PTK_K - cs;
        int chunkpref = 0;
#pragma unroll
        for (int c = 0; c < 4; ++c) {
            unsigned long long tb[4];
#pragma unroll
            for (int r = 0; r < 4; ++r) tb[r] = __ballot(tie_[c * 4 + r]);
            int laneb = 0;
#pragma unroll
            for (int r = 0; r < 4; ++r) laneb += lanes_below(tb[r]);
            int local = 0;
#pragma unroll
            for (int r = 0; r < 4; ++r) {
                int before = chunkpref + laneb + local;
                inf_[c * 4 + r] = strict_[c * 4 + r] ||
                                  (tie_[c * 4 + r] && before < need);
                local += tie_[c * 4 + r] ? 1 : 0;
            }
#pragma unroll
            for (int r = 0; r < 4; ++r) chunkpref += __popcll(tb[r]);
        }
    }
}

__device__ __forceinline__ void load_perturb(const float* __restrict__ x,
                                             const float* __restrict__ noise,
                                             int s, int b, int lane, float v[16]) {
    const float4* nz = (const float4*)(noise + (size_t)s * PTK_D);
    const float4* xr = (const float4*)(x + (size_t)b * PTK_D);
#pragma unroll
    for (int c = 0; c < 4; ++c) {
        float4 n4 = nz[c * 64 + lane];
        float4 x4 = xr[c * 64 + lane];
        // mul-then-add, unfused, to bit-match the numpy fp32 reference
        v[c * 4 + 0] = __fadd_rn(x4.x, __fmul_rn(n4.x, PTK_SIGMA));
        v[c * 4 + 1] = __fadd_rn(x4.y, __fmul_rn(n4.y, PTK_SIGMA));
        v[c * 4 + 2] = __fadd_rn(x4.z, __fmul_rn(n4.z, PTK_SIGMA));
        v[c * 4 + 3] = __fadd_rn(x4.w, __fmul_rn(n4.w, PTK_SIGMA));
    }
}

// ---------- Pass 1: per-sample top-16 -> u16 indices, ws[b][rank][n] ----------
__global__ __launch_bounds__(256) void ptk_topk(const float* __restrict__ x,
                                                const float* __restrict__ noise,
                                                unsigned short* __restrict__ topk) {
    const int lane = threadIdx.x & 63;
    const int wv   = threadIdx.x >> 6;
    const int s    = blockIdx.x * 4 + wv;      // sample id (grid exact: 4000*4)
    const int b    = s / PTK_N;
    const int n    = s - b * PTK_N;

    float v[16];
    load_perturb(x, noise, s, b, lane, v);

    bool inf_[16];
    select_top16(v, inf_);

    // rank by ascending global index via ballot-prefix; store u16 idx at
    // ws[(b*K + rank)*N + n]  (transposed so pass-2 reads are coalesced)
    unsigned short* dst = topk + (size_t)b * PTK_K * PTK_N + n;
    int chunkpref = 0;
#pragma unroll
    for (int c = 0; c < 4; ++c) {
        unsigned long long ib[4];
#pragma unroll
        for (int r = 0; r < 4; ++r) ib[r] = __ballot(inf_[c * 4 + r]);
        int laneb = 0;
#pragma unroll
        for (int r = 0; r < 4; ++r) laneb += lanes_below(ib[r]);
        int local = 0;
#pragma unroll
        for (int r = 0; r < 4; ++r) {
            if (inf_[c * 4 + r]) {
                int rank = chunkpref + laneb + local;
                int g    = c * 256 + lane * 4 + r;
                dst[(size_t)rank * PTK_N] = (unsigned short)g;
            }
            local += inf_[c * 4 + r] ? 1 : 0;
        }
#pragma unroll
        for (int r = 0; r < 4; ++r) chunkpref += __popcll(ib[r]);
    }
}

// ---------- Pass 2: per-(b,rank) histogram -> out row ----------
__global__ __launch_bounds__(256) void ptk_hist(const unsigned short* __restrict__ topk,
                                                float* __restrict__ out) {
    const int br   = blockIdx.x;               // 0..511 = b*16 + rank
    const int t    = threadIdx.x;

    __shared__ unsigned int hist[PTK_D];
    ((uint4*)hist)[t] = uint4{0u, 0u, 0u, 0u}; // 256 * 16B = 4 KB exactly
    __syncthreads();

    const unsigned short* src = topk + (size_t)br * PTK_N;  // coalesced u16
    for (int n = t; n < PTK_N; n += 256)
        atomicAdd(&hist[src[n]], 1u);
    __syncthreads();

    uint4 h = ((uint4*)hist)[t];
    float4 o;
    o.x = g_tbl.v[h.x];
    o.y = g_tbl.v[h.y];
    o.z = g_tbl.v[h.z];
    o.w = g_tbl.v[h.w];
    ((float4*)(out + (size_t)br * PTK_D))[t] = o;
}

// ---------- Fallback: single kernel with global atomics (ws unavailable) ----------
__global__ __launch_bounds__(256) void ptk_fallback(const float* __restrict__ x,
                                                    const float* __restrict__ noise,
                                                    float* __restrict__ out) {
    const int lane = threadIdx.x & 63;
    const int wv   = threadIdx.x >> 6;
    const int s    = blockIdx.x * 4 + wv;
    const int b    = s / PTK_N;

    float v[16];
    load_perturb(x, noise, s, b, lane, v);

    bool inf_[16];
    select_top16(v, inf_);

    float* outb = out + (size_t)b * PTK_K * PTK_D;
    int chunkpref = 0;
#pragma unroll
    for (int c = 0; c < 4; ++c) {
        unsigned long long ib[4];
#pragma unroll
        for (int r = 0; r < 4; ++r) ib[r] = __ballot(inf_[c * 4 + r]);
        int laneb = 0;
#pragma unroll
        for (int r = 0; r < 4; ++r) laneb += lanes_below(ib[r]);
        int local = 0;
#pragma unroll
        for (int r = 0; r < 4; ++r) {
            if (inf_[c * 4 + r]) {
                int rank = chunkpref + laneb + local;
                int g    = c * 256 + lane * 4 + r;
                atomicAdd(outb + (size_t)rank * PTK_D + g, 1.0f / (float)PTK_N);
            }
            local += inf_[c * 4 + r] ? 1 : 0;
        }
#pragma unroll
        for (int r = 0; r < 4; ++r) chunkpref += __popcll(ib[r]);
    }
}

extern "C" void kernel_launch(void* const* d_in, const int* in_sizes, int n_in,
                              void* d_out, int out_size, void* d_ws, size_t ws_size,
                              hipStream_t stream) {
    const float* x     = (const float*)d_in[0];
    const float* noise = (const float*)d_in[1];
    float*       out   = (float*)d_out;

    const int samples = PTK_B * PTK_N;                       // 16000
    const size_t ws_needed = (size_t)samples * PTK_K * sizeof(unsigned short); // 512 KB

    if (d_ws != nullptr && ws_size >= ws_needed) {
        unsigned short* topk = (unsigned short*)d_ws;
        // pass 2 writes every out element -> no memset needed
        ptk_topk<<<samples / 4, 256, 0, stream>>>(x, noise, topk);
        ptk_hist<<<PTK_B * PTK_K, 256, 0, stream>>>(topk, out);
    } else {
        // harness poisons d_out with 0xAA before every timed launch
        hipMemsetAsync(out, 0, (size_t)out_size * sizeof(float), stream);
        ptk_fallback<<<samples / 4, 256, 0, stream>>>(x, noise, out);
    }
}

// Round 4
// 103.206 us; speedup vs baseline: 1.1872x; 1.0031x over previous
//
#include <hip/hip_runtime.h>

// PerturbedTopK: B=32, N=500, D=1024, K=16, sigma=0.05
// out[b, rank, idx] += 1/N for each sample's top-K (rank = ascending-index order).
//
// R6 = R5 minus the workspace: scratch lives INSIDE the output buffer.
//   The harness poisons the 256 MB workspace with a 43 us fill (77% HBM peak)
//   every timed iteration -- 3x our total kernel time. We only need 512 KB of
//   scratch, and pass-2's consumption is perfectly nested in its production:
//   block br reads exactly the 500 u16 indices of row br, then overwrites that
//   row. So pass-1 stores the u16 index list into the FIRST 1000 BYTES of
//   out-row br (poisoned garbage at that point), and pass-2 reads its own
//   row's scratch (all reads before __syncthreads) then overwrites the full
//   row with floats. No workspace, no memset, no inter-block hazard.
//
//   Pass 1 (per sample = one wave, no LDS, no barriers, no sort):
//     1. perturb v = x + 0.05*noise (unfused, bit-matches numpy)
//     2. bisect threshold T until count(v > T) == 16 exactly (tie fallback)
//     3. rank via ballot+mbcnt prefix in global-index order
//     4. store u16 index at scratch(row=b*16+rank, col=n)
//   Pass 2 (one block per (b, rank) row, 512 blocks):
//     LDS u32 histogram of the row's 500 indices; out[d] = tbl[count] where
//     tbl[k] = k-fold ITERATED fp32 sum of 1/N (compile-time constexpr --
//     clang constexpr fp32 is exact IEEE-RN, bit-identical to the reference's
//     repeated scatter-add; integer counts are order-independent).
//
// History: R3 removed the bitonic sort (50->44 us); R4 removed the contended
// fp32 atomic scatter (~500-deep cross-XCD RMW chains ~= 40 us); R5 removed
// the per-block 500-dep-chain table build + transposed scratch. Kernels are
// ~13 us combined; this round attacks the harness's 256 MB ws poison fill.

#define PTK_K     16
#define PTK_N     500
#define PTK_B     32
#define PTK_D     1024
#define PTK_SIGMA 0.05f

// ---- compile-time iterated-add table: tbl.v[k] = k-fold fp32 sum of 1/N ----
struct PtkTbl { float v[PTK_N + 1]; };
static constexpr PtkTbl make_tbl() {
    PtkTbl t{};
    float s = 0.0f;
    t.v[0] = 0.0f;
    for (int k = 1; k <= PTK_N; ++k) {
        s = s + (1.0f / (float)PTK_N);   // constexpr fp32: exact IEEE RN
        t.v[k] = s;
    }
    return t;
}
__device__ __constant__ PtkTbl g_tbl = make_tbl();

__device__ __forceinline__ int lanes_below(unsigned long long m) {
    return __builtin_amdgcn_mbcnt_hi((unsigned)(m >> 32),
           __builtin_amdgcn_mbcnt_lo((unsigned)m, 0u));
}

// ---------- per-wave top-16 selection ----------
// Membership flags inf_[16] (exactly 16 set across the wave) for the 16
// elements v[] owned by this lane.
__device__ __forceinline__ void select_top16(const float v[16], bool inf_[16]) {
    auto countGT = [&](float T) {
        int cnt = 0;
#pragma unroll
        for (int i = 0; i < 16; ++i)
            cnt += __popcll(__ballot(v[i] > T));   // wave-uniform scalar count
        return cnt;
    };

    // bisect to count(v > T) == 16 exactly.
    // |v| < 5 for Gaussian data; [-16,16] brackets everything.
    // Invariant: count(>lo) > 16 > count(>hi).
    float lo = -16.0f, hi = 16.0f;
    float Tsel = 0.0f;
    bool  exact = false;
    for (int it = 0; it < 200; ++it) {
        float T;
        if      (it == 0) T = 1.80f;            // +-4sigma bracket of the 16th
        else if (it == 1) T = 2.55f;            // order stat of N(0,1), D=1024
        else              T = 0.5f * (lo + hi);
        if (T <= lo || T >= hi) {
            if (it < 2) continue;               // probe outside bracket: skip
            break;                              // interval collapsed -> ties
        }
        int cnt = countGT(T);
        if (cnt == PTK_K) { Tsel = T; exact = true; break; }
        if (cnt > PTK_K) lo = T; else hi = T;
    }

    if (exact) {
#pragma unroll
        for (int i = 0; i < 16; ++i) inf_[i] = v[i] > Tsel;
    } else {
        // collapsed: candidates in (lo, hi] share one value; fill remaining
        // slots by lowest global index (stable top_k tie-break)
        bool strict_[16], tie_[16];
        int cs = 0;
#pragma unroll
        for (int i = 0; i < 16; ++i) {
            strict_[i] = v[i] > hi;
            cs += __popcll(__ballot(strict_[i]));
            tie_[i] = (v[i] > lo) && !strict_[i];
        }
        const int need = PTK_K - cs;
        int chunkpref = 0;
#pragma unroll
        for (int c = 0; c < 4; ++c) {
            unsigned long long tb[4];
#pragma unroll
            for (int r = 0; r < 4; ++r) tb[r] = __ballot(tie_[c * 4 + r]);
            int laneb = 0;
#pragma unroll
            for (int r = 0; r < 4; ++r) laneb += lanes_below(tb[r]);
            int local = 0;
#pragma unroll
            for (int r = 0; r < 4; ++r) {
                int before = chunkpref + laneb + local;
                inf_[c * 4 + r] = strict_[c * 4 + r] ||
                                  (tie_[c * 4 + r] && before < need);
                local += tie_[c * 4 + r] ? 1 : 0;
            }
#pragma unroll
            for (int r = 0; r < 4; ++r) chunkpref += __popcll(tb[r]);
        }
    }
}

__device__ __forceinline__ void load_perturb(const float* __restrict__ x,
                                             const float* __restrict__ noise,
                                             int s, int b, int lane, float v[16]) {
    const float4* nz = (const float4*)(noise + (size_t)s * PTK_D);
    const float4* xr = (const float4*)(x + (size_t)b * PTK_D);
#pragma unroll
    for (int c = 0; c < 4; ++c) {
        float4 n4 = nz[c * 64 + lane];
        float4 x4 = xr[c * 64 + lane];
        // mul-then-add, unfused, to bit-match the numpy fp32 reference
        v[c * 4 + 0] = __fadd_rn(x4.x, __fmul_rn(n4.x, PTK_SIGMA));
        v[c * 4 + 1] = __fadd_rn(x4.y, __fmul_rn(n4.y, PTK_SIGMA));
        v[c * 4 + 2] = __fadd_rn(x4.z, __fmul_rn(n4.z, PTK_SIGMA));
        v[c * 4 + 3] = __fadd_rn(x4.w, __fmul_rn(n4.w, PTK_SIGMA));
    }
}

// ---------- Pass 1: per-sample top-16 -> u16 scratch inside out rows ----------
// scratch(row, n) = u16 at byte offset row*4096 + n*2 of out (first 1000 B of
// each 4 KB out row; out is harness-poisoned garbage until pass 2 rewrites it).
__global__ __launch_bounds__(256) void ptk_topk(const float* __restrict__ x,
                                                const float* __restrict__ noise,
                                                float* __restrict__ out) {
    const int lane = threadIdx.x & 63;
    const int wv   = threadIdx.x >> 6;
    const int s    = blockIdx.x * 4 + wv;      // sample id (grid exact: 4000*4)
    const int b    = s / PTK_N;
    const int n    = s - b * PTK_N;

    float v[16];
    load_perturb(x, noise, s, b, lane, v);

    bool inf_[16];
    select_top16(v, inf_);

    // rank by ascending global index via ballot-prefix; store u16 idx at
    // scratch(b*16+rank, n)
    unsigned short* sbase = (unsigned short*)(out + (size_t)b * PTK_K * PTK_D) + n;
    int chunkpref = 0;
#pragma unroll
    for (int c = 0; c < 4; ++c) {
        unsigned long long ib[4];
#pragma unroll
        for (int r = 0; r < 4; ++r) ib[r] = __ballot(inf_[c * 4 + r]);
        int laneb = 0;
#pragma unroll
        for (int r = 0; r < 4; ++r) laneb += lanes_below(ib[r]);
        int local = 0;
#pragma unroll
        for (int r = 0; r < 4; ++r) {
            if (inf_[c * 4 + r]) {
                int rank = chunkpref + laneb + local;
                int g    = c * 256 + lane * 4 + r;
                sbase[(size_t)rank * (PTK_D * 2)] = (unsigned short)g;  // row stride 4KB = 2048 u16
            }
            local += inf_[c * 4 + r] ? 1 : 0;
        }
#pragma unroll
        for (int r = 0; r < 4; ++r) chunkpref += __popcll(ib[r]);
    }
}

// ---------- Pass 2: per-(b,rank) histogram of own-row scratch -> out row ----------
__global__ __launch_bounds__(256) void ptk_hist(float* __restrict__ out) {
    const int br = blockIdx.x;                 // 0..511 = b*16 + rank
    const int t  = threadIdx.x;

    __shared__ unsigned int hist[PTK_D];
    ((uint4*)hist)[t] = uint4{0u, 0u, 0u, 0u}; // 256 * 16B = 4 KB exactly
    __syncthreads();

    // read this row's 500 u16 indices (coalesced); all reads complete before
    // the barrier, so the float overwrite below cannot race them.
    const unsigned short* src = (const unsigned short*)(out + (size_t)br * PTK_D);
    for (int n = t; n < PTK_N; n += 256)
        atomicAdd(&hist[src[n]], 1u);
    __syncthreads();

    uint4 h = ((uint4*)hist)[t];
    float4 o;
    o.x = g_tbl.v[h.x];
    o.y = g_tbl.v[h.y];
    o.z = g_tbl.v[h.z];
    o.w = g_tbl.v[h.w];
    ((float4*)(out + (size_t)br * PTK_D))[t] = o;
}

extern "C" void kernel_launch(void* const* d_in, const int* in_sizes, int n_in,
                              void* d_out, int out_size, void* d_ws, size_t ws_size,
                              hipStream_t stream) {
    const float* x     = (const float*)d_in[0];
    const float* noise = (const float*)d_in[1];
    float*       out   = (float*)d_out;

    const int samples = PTK_B * PTK_N;          // 16000
    // no workspace use, no memset: scratch lives in out, pass 2 rewrites all
    ptk_topk<<<samples / 4, 256, 0, stream>>>(x, noise, out);
    ptk_hist<<<PTK_B * PTK_K, 256, 0, stream>>>(out);
}